// Round 3
// baseline (48.982 us; speedup 1.0000x reference)
//
#include <hip/hip_runtime.h>

#define BB 16
#define TT 1024
#define HH 14
#define WW 14
#define CC 16

constexpr int FL4_PER_T     = HH * WW * CC / 4;             // 784
constexpr int FL4_PER_BATCH = TT * FL4_PER_T;               // 802816
constexpr int CHUNKS_PER_B  = 112;
constexpr int FL4_PER_CHUNK = FL4_PER_BATCH / CHUNKS_PER_B; // 7168
constexpr int THREADS       = 256;
constexpr int ITERS         = FL4_PER_CHUNK / THREADS;      // 28
constexpr int NBLOCKS       = BB * CHUNKS_PER_B;            // 1792 = 7 blocks/CU exactly

// d_ws layout (floats):
//   act partials [0, 28672), blk partials [28672, 57344), kl partials [57344, 59136)
constexpr int WS_BLK_OFF = NBLOCKS * CC;                    // 28672
constexpr int WS_KL_OFF  = 2 * NBLOCKS * CC;                // 57344

#define EPSF      1e-7f
#define INV_H     (1.0f / 14.0f)
#define LN_INV_H  (-2.63905732962f)   /* ln(1/14) */

__device__ __forceinline__ void active_body(const float4 x,
    float& a0, float& a1, float& a2, float& a3, float& kl)
{
    a0 += x.x; a1 += x.y; a2 += x.z; a3 += x.w;
    float l0 = __logf(fminf(fmaxf(x.x, EPSF), 1.0f));
    float l1 = __logf(fminf(fmaxf(x.y, EPSF), 1.0f));
    float l2 = __logf(fminf(fmaxf(x.z, EPSF), 1.0f));
    float l3 = __logf(fminf(fmaxf(x.w, EPSF), 1.0f));
    kl += 4.0f * LN_INV_H - (l0 + l1 + l2 + l3);
}

__global__ __launch_bounds__(THREADS, 7)   // 7 blocks/CU = 28 waves/CU, caps VGPR<=72
void ttv_sums_kernel(const float* __restrict__ cam,
                     const int*   __restrict__ length,
                     float* __restrict__ part)
{
    const int bid   = (int)blockIdx.x;
    const int b     = bid / CHUNKS_PER_B;
    const int chunk = bid - b * CHUNKS_PER_B;
    const int len   = length[b];

    const int s0 = chunk * FL4_PER_CHUNK;        // first float4 idx (within batch)
    const int t0 = s0 / FL4_PER_T;               // first t touched
    const int t1 = (s0 + FL4_PER_CHUNK - 1) / FL4_PER_T; // last t touched

    const float4* __restrict__ base =
        reinterpret_cast<const float4*>(cam) + (size_t)b * FL4_PER_BATCH + s0;

    float a0 = 0.f, a1 = 0.f, a2 = 0.f, a3 = 0.f;   // active channel-group sums
    float q0 = 0.f, q1 = 0.f, q2 = 0.f, q3 = 0.f;   // blank channel-group sums
    float kl = 0.f;

    int idx = (int)threadIdx.x;   // idx % 4 constant per thread -> fixed 4-channel group

    if (t1 < len) {
        // fully active chunk: no division, no branch
        #pragma unroll 4
        for (int it = 0; it < ITERS; ++it, idx += THREADS) {
            float4 x = base[idx];
            active_body(x, a0, a1, a2, a3, kl);
        }
    } else if (t0 >= len) {
        // fully blank chunk: pure streaming adds
        #pragma unroll 4
        for (int it = 0; it < ITERS; ++it, idx += THREADS) {
            float4 x = base[idx];
            q0 += x.x; q1 += x.y; q2 += x.z; q3 += x.w;
        }
    } else {
        // mixed chunk (at most one per batch)
        #pragma unroll 4
        for (int it = 0; it < ITERS; ++it, idx += THREADS) {
            float4 x = base[idx];
            int t = (s0 + idx) / FL4_PER_T;
            if (t < len) {
                active_body(x, a0, a1, a2, a3, kl);
            } else {
                q0 += x.x; q1 += x.y; q2 += x.z; q3 += x.w;
            }
        }
    }

    // wave-level reduce: sum lanes sharing (lane & 3); lanes 0..3 then hold
    // channel groups {0-3},{4-7},{8-11},{12-15}
    #pragma unroll
    for (int off = 4; off <= 32; off <<= 1) {
        a0 += __shfl_xor(a0, off); a1 += __shfl_xor(a1, off);
        a2 += __shfl_xor(a2, off); a3 += __shfl_xor(a3, off);
        q0 += __shfl_xor(q0, off); q1 += __shfl_xor(q1, off);
        q2 += __shfl_xor(q2, off); q3 += __shfl_xor(q3, off);
    }
    #pragma unroll
    for (int off = 1; off <= 32; off <<= 1) kl += __shfl_xor(kl, off);

    __shared__ float s_red[2 * CC + 1];
    if (threadIdx.x < 2 * CC + 1) s_red[threadIdx.x] = 0.f;
    __syncthreads();

    const int lane = (int)(threadIdx.x & 63u);
    if (lane < 4) {
        const int cb = lane * 4;
        atomicAdd(&s_red[cb + 0], a0); atomicAdd(&s_red[cb + 1], a1);
        atomicAdd(&s_red[cb + 2], a2); atomicAdd(&s_red[cb + 3], a3);
        atomicAdd(&s_red[CC + cb + 0], q0); atomicAdd(&s_red[CC + cb + 1], q1);
        atomicAdd(&s_red[CC + cb + 2], q2); atomicAdd(&s_red[CC + cb + 3], q3);
    }
    if (lane == 0) atomicAdd(&s_red[2 * CC], kl * INV_H);
    __syncthreads();

    if (threadIdx.x < CC) {
        part[bid * CC + (int)threadIdx.x] = s_red[threadIdx.x];
    } else if (threadIdx.x < 2 * CC) {
        part[WS_BLK_OFF + bid * CC + (int)threadIdx.x - CC] = s_red[threadIdx.x];
    } else if (threadIdx.x == 2 * CC) {
        part[WS_KL_OFF + bid] = s_red[2 * CC];
    }
}

// One block, 1024 threads (16 waves). tid = (b*16 + c)*4 + s ; s in 0..3.
// Wave w holds exactly batch b = w (64 lanes = 16 channels x 4 s-slices).
__global__ __launch_bounds__(1024)
void ttv_finalize_kernel(const float* __restrict__ part,
                         const float* __restrict__ count,
                         float* __restrict__ out)
{
    const int tid  = (int)threadIdx.x;
    const int s    = tid & 3;
    const int pair = tid >> 2;        // b*16 + c
    const int b    = pair >> 4;
    const int c    = pair & 15;

    constexpr int K_PER_S = CHUNKS_PER_B / 4;   // 28

    float as = 0.f, bs = 0.f;
    #pragma unroll 4
    for (int k = s * K_PER_S; k < (s + 1) * K_PER_S; ++k) {
        const int row = (b * CHUNKS_PER_B + k) * CC + c;
        as += part[row];
        bs += part[WS_BLK_OFF + row];
    }
    // sum over the 4 s-slices (tid bits 0..1) -> all 4 lanes get the total
    #pragma unroll
    for (int off = 1; off <= 2; off <<= 1) {
        as += __shfl_xor(as, off);
        bs += __shfl_xor(bs, off);
    }

    // kl: 1792 partials over 1024 threads, then block reduction
    float kl = part[WS_KL_OFF + tid] + ((tid < NBLOCKS - 1024) ? part[WS_KL_OFF + 1024 + tid] : 0.f);
    #pragma unroll
    for (int off = 1; off <= 32; off <<= 1) kl += __shfl_xor(kl, off);
    __shared__ float s_kl[16];
    if ((tid & 63) == 0) s_kl[tid >> 6] = kl;
    __syncthreads();
    float klsum = 0.f;
    #pragma unroll
    for (int w = 0; w < 16; ++w) klsum += s_kl[w];

    const float cnt = count[pair];
    // huber(count, active_sum), DELTA = 1
    float ea = fabsf(as - cnt);
    float qa = fminf(ea, 1.0f);
    float ha = 0.5f * qa * qa + (ea - qa);
    // huber(0, blank_sum)
    float eb = fabsf(bs);
    float qb = fminf(eb, 1.0f);
    float hb = 0.5f * qb * qb + (eb - qb);

    float h = ha + hb;   // identical across the 4 s-lanes
    // sum over c (tid bits 2..5): offsets 4,8,16,32 within the wave
    #pragma unroll
    for (int off = 4; off <= 32; off <<= 1) h += __shfl_xor(h, off);

    if ((tid & 63) == 0) {
        const float kl_loss = klsum * (0.1f / (float)(BB * TT * HH * WW));
        out[b] = h * (1.0f / 16.0f) + kl_loss;
    }
}

extern "C" void kernel_launch(void* const* d_in, const int* in_sizes, int n_in,
                              void* d_out, int out_size, void* d_ws, size_t ws_size,
                              hipStream_t stream)
{
    const float* cam    = (const float*)d_in[0];
    const float* count  = (const float*)d_in[1];
    const int*   length = (const int*)d_in[2];
    float* out  = (float*)d_out;
    float* part = (float*)d_ws;   // 59136 floats = 231 KB

    ttv_sums_kernel<<<NBLOCKS, THREADS, 0, stream>>>(cam, length, part);
    ttv_finalize_kernel<<<1, 1024, 0, stream>>>(part, count, out);
}